// Round 13
// baseline (107.893 us; speedup 1.0000x reference)
//
#include <hip/hip_runtime.h>
#include <math.h>

#define N_NODES 50000
#define N_EDGES 800000
#define IN_DIM 256
#define OUT_DIM 128
#define ALPHA 0.2f

#define NPART 32             // dst-counter partitions; x = block&31 keeps XCD affinity (x%8)
#define ZERO_NB 1563         // zero deg32: 1563*256*4 ints >= 1,600,000
#define WT_NB   16
#define GEMM_NB 391          // ceil(50000/128), 8 waves, 16 rows/wave
#define DEG_NB  1563         // ceil(800000/512)
#define SCAN_NB 196          // (N_NODES+255)/256

typedef __attribute__((ext_vector_type(8))) short short8;
typedef __attribute__((ext_vector_type(4))) float f32x4;
typedef __attribute__((ext_vector_type(2))) float f32x2;

// ---------------- workspace layout (bytes) ----------------
#define OFF_ZB    0u          // z bf16: 12,800,000
#define OFF_S1    12800000u
#define OFF_S2    13000000u
#define OFF_DEG32 13200000u   // 32 * 50000 * 4 = 6,400,000
#define OFF_OFFS  19600000u
#define OFF_OFFS2 19800000u   // 50001 ints
#define OFF_BSUM  20000064u
#define OFF_RANK  20001088u   // u16
#define OFF_SRCS  21601088u   // u16
#define OFF_WT    23201088u   // 65,536
#define OFF_PRE32 23266624u   // u16: 50000*32*2 = 3,200,000
// total ~26.5 MB

static __device__ __forceinline__ unsigned short f2bf_rne(float f) {
    unsigned int u = __float_as_uint(f);
    unsigned int r = (u + 0x7FFFu + ((u >> 16) & 1u)) >> 16;
    return (unsigned short)r;
}
static __device__ __forceinline__ unsigned int pack2bf(float lo, float hi) {
    return (unsigned int)f2bf_rne(lo) | ((unsigned int)f2bf_rne(hi) << 16);
}

// ---------------- init: zero deg32 | WT transpose ----------------
__global__ __launch_bounds__(256) void init_wt(const float* __restrict__ W,
                                               int* __restrict__ deg32,
                                               unsigned short* __restrict__ WT) {
    int b = blockIdx.x, t = threadIdx.x;
    if (b < ZERO_NB) {
        int i = (b * 256 + t) * 4;
        if (i < NPART * N_NODES)
            *(int4*)(deg32 + i) = make_int4(0, 0, 0, 0);
    } else {
        int idx = ((b - ZERO_NB) * 256 + t) * 8;   // WT[c][k] = bf16(W[k][c])
        int c = idx >> 8, k0 = idx & 255;
        unsigned int uu[4];
#pragma unroll
        for (int q = 0; q < 4; q++) {
            float lo = W[(size_t)(k0 + 2 * q) * OUT_DIM + c];
            float hi = W[(size_t)(k0 + 2 * q + 1) * OUT_DIM + c];
            uu[q] = pack2bf(lo, hi);
        }
        *(uint4*)(WT + idx) = make_uint4(uu[0], uu[1], uu[2], uu[3]);
    }
}

// ---------------- fused: GEMM (32KB LDS, two-phase B) | deg+rank (32 partitions) ----------------
// R12 lesson: 8-partition atomics serialize ~32 same-line ops per L2 line (~25us).
// 32 partitions cut that 4x while keeping XCD affinity (x%8 == block%8).
__global__ __launch_bounds__(512) void gemm_deg(const float* __restrict__ h,
                                                const unsigned short* __restrict__ WT,
                                                const float* __restrict__ attn,
                                                unsigned short* __restrict__ zb,
                                                float* __restrict__ s1,
                                                float* __restrict__ s2,
                                                const int* __restrict__ dst,
                                                int* __restrict__ deg32,
                                                unsigned short* __restrict__ rank) {
    __shared__ char smem[32768];
    const int t = threadIdx.x;

    if (blockIdx.x >= GEMM_NB) {       // ---- deg_rank path (no LDS use) ----
        int bb = blockIdx.x - GEMM_NB;
        int e = bb * 512 + t;
        int x = bb & (NPART - 1);
        if (e < N_EDGES)
            rank[e] = (unsigned short)atomicAdd(&deg32[x * N_NODES + dst[e]], 1);
        return;
    }

    // ---- GEMM path: tile 128x128, K=256 in two 32KB halves ----
    const int lane = t & 63, w = t >> 6;
    const int row0 = blockIdx.x * 128;
    const int m16 = lane & 15, kb = lane >> 4;

    const int rA = row0 + w * 16 + m16;
    const float* hrow = h + (size_t)min(rA, N_NODES - 1) * IN_DIM + kb * 8;

    f32x4 acc[8];
#pragma unroll
    for (int ct = 0; ct < 8; ct++) acc[ct] = (f32x4){0.f, 0.f, 0.f, 0.f};

    float4 v0 = *(const float4*)(hrow);
    float4 v1 = *(const float4*)(hrow + 4);

#pragma unroll
    for (int half = 0; half < 2; half++) {
        if (half) __syncthreads();     // protect overwrite of half-0 data
#pragma unroll
        for (int q = 0; q < 4; q++) {
            int G = t * 4 + q;                  // 0..2047
            int cc = G >> 4, gs = G & 15;       // col 0..127, granule 0..15
            const uint4 v = *(const uint4*)(WT + (size_t)cc * IN_DIM + half * 128 + gs * 8);
            *(uint4*)(smem + cc * 256 + ((gs ^ (cc & 7)) * 16)) = v;
        }
        __syncthreads();
#pragma unroll
        for (int kcl = 0; kcl < 4; kcl++) {
            const float4 c0 = v0, c1 = v1;
            int nk = half * 4 + kcl + 1;
            if (nk < 8) {
                v0 = *(const float4*)(hrow + nk * 32);
                v1 = *(const float4*)(hrow + nk * 32 + 4);
            }
            short8 af;
            af[0] = (short)f2bf_rne(c0.x); af[1] = (short)f2bf_rne(c0.y);
            af[2] = (short)f2bf_rne(c0.z); af[3] = (short)f2bf_rne(c0.w);
            af[4] = (short)f2bf_rne(c1.x); af[5] = (short)f2bf_rne(c1.y);
            af[6] = (short)f2bf_rne(c1.z); af[7] = (short)f2bf_rne(c1.w);
            const char* bbase = smem + m16 * 256 + (((kcl * 4 + kb) ^ (m16 & 7)) * 16);
#pragma unroll
            for (int ct = 0; ct < 8; ct++) {
                const short8 bf = *(const short8*)(bbase + ct * 4096);
                acc[ct] = __builtin_amdgcn_mfma_f32_16x16x32_bf16(af, bf, acc[ct], 0, 0, 0);
            }
        }
    }

    // ---- epilogue: s1/s2 from f32 acc, zb bf16 store ----
    float a1v[8], a2v[8];
#pragma unroll
    for (int ct = 0; ct < 8; ct++) {
        a1v[ct] = attn[ct * 16 + m16];
        a2v[ct] = attn[OUT_DIM + ct * 16 + m16];
    }
#pragma unroll
    for (int i = 0; i < 4; i++) {
        int rr = row0 + w * 16 + kb * 4 + i;
        float q1 = 0.f, q2 = 0.f;
#pragma unroll
        for (int ct = 0; ct < 8; ct++) {
            q1 += acc[ct][i] * a1v[ct];
            q2 += acc[ct][i] * a2v[ct];
        }
        q1 += __shfl_xor(q1, 1); q1 += __shfl_xor(q1, 2);
        q1 += __shfl_xor(q1, 4); q1 += __shfl_xor(q1, 8);
        q2 += __shfl_xor(q2, 1); q2 += __shfl_xor(q2, 2);
        q2 += __shfl_xor(q2, 4); q2 += __shfl_xor(q2, 8);
        if (m16 == 0 && rr < N_NODES) { s1[rr] = q1; s2[rr] = q2; }
        if (rr < N_NODES) {
#pragma unroll
            for (int ct = 0; ct < 8; ct++)
                zb[(size_t)rr * OUT_DIM + ct * 16 + m16] = f2bf_rne(acc[ct][i]);
        }
    }
}

// ---------------- scan: sum 32 partitions, emit pre32, chunk-scan totals ----------------
__global__ __launch_bounds__(256) void scan1(const int* __restrict__ deg32,
                                             int* __restrict__ offs,
                                             int* __restrict__ blocksum,
                                             unsigned short* __restrict__ pre32) {
    __shared__ int s[256];
    int t = threadIdx.x;
    int i = blockIdx.x * 256 + t;
    int tot = 0;
    if (i < N_NODES) {
        unsigned short pre[NPART];
#pragma unroll
        for (int x = 0; x < NPART; x++) {
            pre[x] = (unsigned short)tot;
            tot += deg32[x * N_NODES + i];
        }
#pragma unroll
        for (int q = 0; q < NPART / 4; q++) {
            ushort4 p;
            p.x = pre[4 * q]; p.y = pre[4 * q + 1];
            p.z = pre[4 * q + 2]; p.w = pre[4 * q + 3];
            *(ushort4*)(pre32 + (size_t)i * NPART + 4 * q) = p;
        }
    }
    s[t] = tot;
    __syncthreads();
    int v = tot;
    for (int ofs = 1; ofs < 256; ofs <<= 1) {
        int add = (t >= ofs) ? s[t - ofs] : 0;
        __syncthreads();
        v += add;
        s[t] = v;
        __syncthreads();
    }
    if (i < N_NODES) offs[i] = v - tot;
    if (t == 255) blocksum[blockIdx.x] = v;
}

// ---------------- scatter (in-LDS scan of blocksums; emits folded offs2) ----------------
__global__ __launch_bounds__(256) void scatter_k(const int* __restrict__ src, const int* __restrict__ dst,
                                                 const unsigned short* __restrict__ rank,
                                                 const int* __restrict__ offs,
                                                 const int* __restrict__ blocksum,
                                                 const unsigned short* __restrict__ pre32,
                                                 unsigned short* __restrict__ srcs,
                                                 int* __restrict__ offs2) {
    __shared__ int sbo[256];
    int t = threadIdx.x;
    int d0 = (t < SCAN_NB) ? blocksum[t] : 0;
    sbo[t] = d0;
    __syncthreads();
    int v = d0;
    for (int ofs = 1; ofs < 256; ofs <<= 1) {
        int add = (t >= ofs) ? sbo[t - ofs] : 0;
        __syncthreads();
        v += add;
        sbo[t] = v;
        __syncthreads();
    }
    int excl = (t > 0) ? sbo[t - 1] : 0;
    __syncthreads();
    sbo[t] = excl;
    __syncthreads();

    if (blockIdx.x < SCAN_NB) {
        int i = blockIdx.x * 256 + t;
        if (i < N_NODES) offs2[i] = offs[i] + sbo[blockIdx.x];
        if (blockIdx.x == 0 && t == 0) offs2[N_NODES] = N_EDGES;
    }

    int e = blockIdx.x * 256 + t;
    if (e < N_EDGES) {
        int d = dst[e];
        int x = (e >> 9) & (NPART - 1);     // deg block = e/512, partition = block&31
        int pos = offs[d] + sbo[d >> 8] + (int)pre32[((size_t)d << 5) + x] + (int)rank[e];
        srcs[pos] = (unsigned short)src[e];
    }
}

// ---------------- per-dst softmax + weighted gather-sum (unchanged control) ----------------
__global__ __launch_bounds__(256) void aggregate(const unsigned short* __restrict__ zb,
                                                 const int* __restrict__ offs2,
                                                 const unsigned short* __restrict__ srcs,
                                                 const float* __restrict__ s1,
                                                 const float* __restrict__ s2,
                                                 float* __restrict__ out) {
    int wid = (blockIdx.x * blockDim.x + threadIdx.x) >> 6;
    int lane = threadIdx.x & 63;
    if (wid >= N_NODES) return;
    const int g = lane >> 3;
    const int l = lane & 7;
    float* outp = out + (size_t)wid * OUT_DIM + l * 16 + g * 2;

    int base = offs2[wid];
    int len = offs2[wid + 1] - base;
    if (len == 0) {
        *(float2*)outp = make_float2(0.f, 0.f);
        return;
    }
    const float s2v = s2[wid];

    float sum = 0.f;
    f32x2 acc2[8];
#pragma unroll
    for (int k = 0; k < 8; k++) acc2[k] = (f32x2){0.f, 0.f};

    for (int c0 = 0; c0 < len; c0 += 64) {
        int i = c0 + lane;
        float ex = 0.f;
        int sj = 0;
        if (i < len) {
            sj = srcs[base + i];
            float lg = s1[sj] + s2v;
            lg = (lg >= 0.f) ? lg : ALPHA * lg;
            ex = __expf(lg);
        }
        sum += ex;
        int cnt = min(64, len - c0);
        int j0 = 0;
        for (; j0 + 16 <= cnt; j0 += 16) {
            int ja = j0 + g, jb = j0 + 8 + g;
            float wa = __shfl(ex, ja), wb = __shfl(ex, jb);
            int sa = __shfl(sj, ja), sb = __shfl(sj, jb);
            const uint4* rpa = (const uint4*)(zb + (size_t)sa * OUT_DIM);
            const uint4* rpb = (const uint4*)(zb + (size_t)sb * OUT_DIM);
            const uint4 a0 = rpa[l * 2];
            const uint4 a1 = rpa[l * 2 + 1];
            const uint4 b0 = rpb[l * 2];
            const uint4 b1 = rpb[l * 2 + 1];
#pragma unroll
            for (int k = 0; k < 4; k++) {
                unsigned int u = (&a0.x)[k];
                f32x2 f;
                f.x = __uint_as_float(u << 16);
                f.y = __uint_as_float(u & 0xFFFF0000u);
                acc2[k] += wa * f;
                u = (&b0.x)[k];
                f.x = __uint_as_float(u << 16);
                f.y = __uint_as_float(u & 0xFFFF0000u);
                acc2[k] += wb * f;
            }
#pragma unroll
            for (int k = 0; k < 4; k++) {
                unsigned int u = (&a1.x)[k];
                f32x2 f;
                f.x = __uint_as_float(u << 16);
                f.y = __uint_as_float(u & 0xFFFF0000u);
                acc2[4 + k] += wa * f;
                u = (&b1.x)[k];
                f.x = __uint_as_float(u << 16);
                f.y = __uint_as_float(u & 0xFFFF0000u);
                acc2[4 + k] += wb * f;
            }
        }
        for (; j0 < cnt; j0 += 8) {
            int j = j0 + g;
            float wj = __shfl(ex, j);
            int s = __shfl(sj, j);
            if (j < cnt) {
                const uint4* rp = (const uint4*)(zb + (size_t)s * OUT_DIM);
                const uint4 v0 = rp[l * 2];
                const uint4 v1 = rp[l * 2 + 1];
#pragma unroll
                for (int k = 0; k < 4; k++) {
                    unsigned int u = (&v0.x)[k];
                    f32x2 f;
                    f.x = __uint_as_float(u << 16);
                    f.y = __uint_as_float(u & 0xFFFF0000u);
                    acc2[k] += wj * f;
                }
#pragma unroll
                for (int k = 0; k < 4; k++) {
                    unsigned int u = (&v1.x)[k];
                    f32x2 f;
                    f.x = __uint_as_float(u << 16);
                    f.y = __uint_as_float(u & 0xFFFF0000u);
                    acc2[4 + k] += wj * f;
                }
            }
        }
    }
#pragma unroll
    for (int k = 0; k < 8; k++) {
        acc2[k].x += __shfl_xor(acc2[k].x, 8);
        acc2[k].y += __shfl_xor(acc2[k].y, 8);
        acc2[k].x += __shfl_xor(acc2[k].x, 16);
        acc2[k].y += __shfl_xor(acc2[k].y, 16);
        acc2[k].x += __shfl_xor(acc2[k].x, 32);
        acc2[k].y += __shfl_xor(acc2[k].y, 32);
    }
#pragma unroll
    for (int m = 32; m >= 1; m >>= 1) sum += __shfl_xor(sum, m);
    float inv = (sum > 0.f) ? 1.f / sum : 1.f;

    float a0 = acc2[g].x * inv;
    float a1 = acc2[g].y * inv;
    float2 o;
    o.x = (a0 > 0.f) ? a0 : expm1f(a0);
    o.y = (a1 > 0.f) ? a1 : expm1f(a1);
    *(float2*)outp = o;
}

// ---------------- launcher ----------------
extern "C" void kernel_launch(void* const* d_in, const int* in_sizes, int n_in,
                              void* d_out, int out_size, void* d_ws, size_t ws_size,
                              hipStream_t stream) {
    const float* h      = (const float*)d_in[0];
    const int*   src    = (const int*)d_in[1];
    const int*   dst    = (const int*)d_in[2];
    const float* W_fc   = (const float*)d_in[3];
    const float* attn_w = (const float*)d_in[4];
    float* out = (float*)d_out;

    char* ws = (char*)d_ws;
    unsigned short* zb = (unsigned short*)(ws + OFF_ZB);
    float* s1       = (float*)(ws + OFF_S1);
    float* s2       = (float*)(ws + OFF_S2);
    int*   deg32    = (int*)(ws + OFF_DEG32);
    int*   offs     = (int*)(ws + OFF_OFFS);
    int*   offs2    = (int*)(ws + OFF_OFFS2);
    int*   blocksum = (int*)(ws + OFF_BSUM);
    unsigned short* rank  = (unsigned short*)(ws + OFF_RANK);
    unsigned short* srcs  = (unsigned short*)(ws + OFF_SRCS);
    unsigned short* WT    = (unsigned short*)(ws + OFF_WT);
    unsigned short* pre32 = (unsigned short*)(ws + OFF_PRE32);

    init_wt<<<ZERO_NB + WT_NB, 256, 0, stream>>>(W_fc, deg32, WT);
    gemm_deg<<<GEMM_NB + DEG_NB, 512, 0, stream>>>(h, WT, attn_w, zb, s1, s2,
                                                   dst, deg32, rank);
    scan1<<<SCAN_NB, 256, 0, stream>>>(deg32, offs, blocksum, pre32);
    scatter_k<<<(N_EDGES + 255) / 256, 256, 0, stream>>>(src, dst, rank, offs, blocksum,
                                                         pre32, srcs, offs2);
    aggregate<<<(N_NODES * 64) / 256, 256, 0, stream>>>(zb, offs2, srcs, s1, s2, out);
}

// Round 14
// 83.633 us; speedup vs baseline: 1.2901x; 1.2901x over previous
//
#include <hip/hip_runtime.h>
#include <math.h>

#define N_NODES 50000
#define N_EDGES 800000
#define IN_DIM 256
#define OUT_DIM 128
#define ALPHA 0.2f

#define BKT 196              // coarse buckets: dst>>8 (196*256 = 50176 >= 50000)
#define EPB 4096             // edges per hist/scatter block (512 thr * 8)
#define HIST_NB 196          // 196*4096 = 802816 >= 800000
#define GEMM_NB 391          // ceil(50000/128), 8 waves, 16 rows/wave

typedef __attribute__((ext_vector_type(8))) short short8;
typedef __attribute__((ext_vector_type(4))) float f32x4;
typedef __attribute__((ext_vector_type(2))) float f32x2;

// ---------------- workspace layout (bytes) ----------------
#define OFF_ZB    0u          // z bf16: 12,800,000
#define OFF_S1    12800000u
#define OFF_S2    13000000u
#define OFF_OFFS2 13200000u   // 50001 ints
#define OFF_WT    13400064u   // 65,536
#define OFF_HIST  13465600u   // 196*196*4 = 153,664
#define OFF_BBASE 13619264u   // 153,664
#define OFF_BTOT  13772928u   // 196*4 (pad to 784)
#define OFF_TMP   13773712u   // u32 packed edges: 3,200,000
#define OFF_SRCS  16973712u   // u16: 1,600,000
// total ~18.6 MB

static __device__ __forceinline__ unsigned short f2bf_rne(float f) {
    unsigned int u = __float_as_uint(f);
    unsigned int r = (u + 0x7FFFu + ((u >> 16) & 1u)) >> 16;
    return (unsigned short)r;
}
static __device__ __forceinline__ unsigned int pack2bf(float lo, float hi) {
    return (unsigned int)f2bf_rne(lo) | ((unsigned int)f2bf_rne(hi) << 16);
}

// ---------------- L0: WT[c][k] = bf16(W[k][c]) ----------------
__global__ __launch_bounds__(256) void wt_k(const float* __restrict__ W,
                                            unsigned short* __restrict__ WT) {
    int idx = (blockIdx.x * 256 + threadIdx.x) * 8;
    int c = idx >> 8, k0 = idx & 255;
    unsigned int uu[4];
#pragma unroll
    for (int q = 0; q < 4; q++) {
        float lo = W[(size_t)(k0 + 2 * q) * OUT_DIM + c];
        float hi = W[(size_t)(k0 + 2 * q + 1) * OUT_DIM + c];
        uu[q] = pack2bf(lo, hi);
    }
    *(uint4*)(WT + idx) = make_uint4(uu[0], uu[1], uu[2], uu[3]);
}

// ---------------- L1: GEMM (32KB LDS, two-phase B) | bucket histogram ----------------
// R13 lesson: 800K global atomic-with-return ~= 1/cy/XCD ~= 42us regardless of
// partitioning. This build uses ONLY LDS atomics (hist path) -> near-free.
__global__ __launch_bounds__(512) void gemm_hist(const float* __restrict__ h,
                                                 const unsigned short* __restrict__ WT,
                                                 const float* __restrict__ attn,
                                                 unsigned short* __restrict__ zb,
                                                 float* __restrict__ s1,
                                                 float* __restrict__ s2,
                                                 const int* __restrict__ dst,
                                                 int* __restrict__ hist) {
    __shared__ char smem[32768];
    const int t = threadIdx.x;

    if (blockIdx.x >= GEMM_NB) {       // ---- histogram path ----
        int hb = blockIdx.x - GEMM_NB;
        int* hcnt = (int*)smem;
        for (int i = t; i < BKT; i += 512) hcnt[i] = 0;
        __syncthreads();
#pragma unroll
        for (int q = 0; q < 8; q++) {
            int e = hb * EPB + q * 512 + t;
            if (e < N_EDGES) atomicAdd(&hcnt[dst[e] >> 8], 1);
        }
        __syncthreads();
        for (int i = t; i < BKT; i += 512) hist[hb * BKT + i] = hcnt[i];
        return;
    }

    // ---- GEMM path: tile 128x128, K=256 in two 32KB halves (unchanged) ----
    const int lane = t & 63, w = t >> 6;
    const int row0 = blockIdx.x * 128;
    const int m16 = lane & 15, kb = lane >> 4;

    const int rA = row0 + w * 16 + m16;
    const float* hrow = h + (size_t)min(rA, N_NODES - 1) * IN_DIM + kb * 8;

    f32x4 acc[8];
#pragma unroll
    for (int ct = 0; ct < 8; ct++) acc[ct] = (f32x4){0.f, 0.f, 0.f, 0.f};

    float4 v0 = *(const float4*)(hrow);
    float4 v1 = *(const float4*)(hrow + 4);

#pragma unroll
    for (int half = 0; half < 2; half++) {
        if (half) __syncthreads();
#pragma unroll
        for (int q = 0; q < 4; q++) {
            int G = t * 4 + q;
            int cc = G >> 4, gs = G & 15;
            const uint4 v = *(const uint4*)(WT + (size_t)cc * IN_DIM + half * 128 + gs * 8);
            *(uint4*)(smem + cc * 256 + ((gs ^ (cc & 7)) * 16)) = v;
        }
        __syncthreads();
#pragma unroll
        for (int kcl = 0; kcl < 4; kcl++) {
            const float4 c0 = v0, c1 = v1;
            int nk = half * 4 + kcl + 1;
            if (nk < 8) {
                v0 = *(const float4*)(hrow + nk * 32);
                v1 = *(const float4*)(hrow + nk * 32 + 4);
            }
            short8 af;
            af[0] = (short)f2bf_rne(c0.x); af[1] = (short)f2bf_rne(c0.y);
            af[2] = (short)f2bf_rne(c0.z); af[3] = (short)f2bf_rne(c0.w);
            af[4] = (short)f2bf_rne(c1.x); af[5] = (short)f2bf_rne(c1.y);
            af[6] = (short)f2bf_rne(c1.z); af[7] = (short)f2bf_rne(c1.w);
            const char* bbase = smem + m16 * 256 + (((kcl * 4 + kb) ^ (m16 & 7)) * 16);
#pragma unroll
            for (int ct = 0; ct < 8; ct++) {
                const short8 bf = *(const short8*)(bbase + ct * 4096);
                acc[ct] = __builtin_amdgcn_mfma_f32_16x16x32_bf16(af, bf, acc[ct], 0, 0, 0);
            }
        }
    }

    float a1v[8], a2v[8];
#pragma unroll
    for (int ct = 0; ct < 8; ct++) {
        a1v[ct] = attn[ct * 16 + m16];
        a2v[ct] = attn[OUT_DIM + ct * 16 + m16];
    }
#pragma unroll
    for (int i = 0; i < 4; i++) {
        int rr = row0 + w * 16 + kb * 4 + i;
        float q1 = 0.f, q2 = 0.f;
#pragma unroll
        for (int ct = 0; ct < 8; ct++) {
            q1 += acc[ct][i] * a1v[ct];
            q2 += acc[ct][i] * a2v[ct];
        }
        q1 += __shfl_xor(q1, 1); q1 += __shfl_xor(q1, 2);
        q1 += __shfl_xor(q1, 4); q1 += __shfl_xor(q1, 8);
        q2 += __shfl_xor(q2, 1); q2 += __shfl_xor(q2, 2);
        q2 += __shfl_xor(q2, 4); q2 += __shfl_xor(q2, 8);
        if (m16 == 0 && rr < N_NODES) { s1[rr] = q1; s2[rr] = q2; }
        if (rr < N_NODES) {
#pragma unroll
            for (int ct = 0; ct < 8; ct++)
                zb[(size_t)rr * OUT_DIM + ct * 16 + m16] = f2bf_rne(acc[ct][i]);
        }
    }
}

// ---------------- L2: column scan of hist -> bbase, btot ----------------
// block b: exclusive scan over blocks of hist[*][b]
__global__ __launch_bounds__(256) void colscan(const int* __restrict__ hist,
                                               int* __restrict__ bbase,
                                               int* __restrict__ btot) {
    __shared__ int s[256];
    int t = threadIdx.x, b = blockIdx.x;
    int d0 = (t < BKT) ? hist[t * BKT + b] : 0;
    s[t] = d0;
    __syncthreads();
    int v = d0;
    for (int ofs = 1; ofs < 256; ofs <<= 1) {
        int add = (t >= ofs) ? s[t - ofs] : 0;
        __syncthreads();
        v += add;
        s[t] = v;
        __syncthreads();
    }
    if (t < BKT) bbase[t * BKT + b] = v - d0;
    if (t == BKT - 1) btot[b] = v;
}

// ---------------- L3: scatter edges into bucketed tmp (packed u32, LDS ranks) ----------------
__global__ __launch_bounds__(512) void scatter_b(const int* __restrict__ src,
                                                 const int* __restrict__ dst,
                                                 const int* __restrict__ bbase,
                                                 const int* __restrict__ btot,
                                                 unsigned int* __restrict__ tmp) {
    __shared__ int s[256];
    __shared__ int bb[BKT];
    __shared__ int bstartL[BKT];
    __shared__ int cur[BKT];
    int t = threadIdx.x, m = blockIdx.x;

    for (int i = t; i < BKT; i += 512) { bb[i] = bbase[m * BKT + i]; cur[i] = 0; }
    int d0 = 0;
    if (t < 256) { d0 = (t < BKT) ? btot[t] : 0; s[t] = d0; }
    __syncthreads();
    int v = d0;
    for (int ofs = 1; ofs < 256; ofs <<= 1) {
        int add = (t < 256 && t >= ofs) ? s[t - ofs] : 0;
        __syncthreads();
        if (t < 256) { v += add; s[t] = v; }
        __syncthreads();
    }
    if (t < BKT) bstartL[t] = v - d0;     // exclusive bucket start
    __syncthreads();

#pragma unroll
    for (int q = 0; q < 8; q++) {
        int e = m * EPB + q * 512 + t;
        if (e < N_EDGES) {
            int d = dst[e];
            int bkt = d >> 8;
            int r = atomicAdd(&cur[bkt], 1);
            tmp[bstartL[bkt] + bb[bkt] + r] =
                ((unsigned int)d << 16) | (unsigned int)src[e];
        }
    }
}

// ---------------- L4: per-bucket counting sort -> srcs (u16) + offs2 ----------------
__global__ __launch_bounds__(512) void bucket_sort(const unsigned int* __restrict__ tmp,
                                                   const int* __restrict__ btot,
                                                   unsigned short* __restrict__ srcs,
                                                   int* __restrict__ offs2) {
    __shared__ int s[256];
    __shared__ int cnt[256];
    __shared__ int cur[256];
    int t = threadIdx.x, b = blockIdx.x;

    int d0 = 0;
    if (t < 256) { d0 = (t < BKT) ? btot[t] : 0; s[t] = d0; cnt[t] = 0; }
    __syncthreads();
    int v = d0;
    for (int ofs = 1; ofs < 256; ofs <<= 1) {
        int add = (t < 256 && t >= ofs) ? s[t - ofs] : 0;
        __syncthreads();
        if (t < 256) { v += add; s[t] = v; }
        __syncthreads();
    }
    __syncthreads();
    const int myCount = btot[b];
    const int myStart = s[b] - myCount;

    // sweep 1: per-node counts within bucket
    for (int i = t; i < myCount; i += 512)
        atomicAdd(&cnt[(tmp[myStart + i] >> 16) & 255], 1);
    __syncthreads();

    // exclusive scan of cnt[256] (reuse s)
    int c0 = 0;
    if (t < 256) { c0 = cnt[t]; s[t] = c0; }
    __syncthreads();
    int cv = c0;
    for (int ofs = 1; ofs < 256; ofs <<= 1) {
        int add = (t < 256 && t >= ofs) ? s[t - ofs] : 0;
        __syncthreads();
        if (t < 256) { cv += add; s[t] = cv; }
        __syncthreads();
    }
    if (t < 256) {
        int excl = cv - c0;
        int node = b * 256 + t;
        if (node < N_NODES) offs2[node] = myStart + excl;
        cur[t] = excl;
    }
    if (b == 0 && t == 0) offs2[N_NODES] = N_EDGES;
    __syncthreads();

    // sweep 2: place src payloads
    for (int i = t; i < myCount; i += 512) {
        unsigned int u = tmp[myStart + i];
        int r = atomicAdd(&cur[(u >> 16) & 255], 1);
        srcs[myStart + r] = (unsigned short)(u & 0xFFFFu);
    }
}

// ---------------- L5: per-dst softmax + weighted gather-sum (unchanged control) ----------------
__global__ __launch_bounds__(256) void aggregate(const unsigned short* __restrict__ zb,
                                                 const int* __restrict__ offs2,
                                                 const unsigned short* __restrict__ srcs,
                                                 const float* __restrict__ s1,
                                                 const float* __restrict__ s2,
                                                 float* __restrict__ out) {
    int wid = (blockIdx.x * blockDim.x + threadIdx.x) >> 6;
    int lane = threadIdx.x & 63;
    if (wid >= N_NODES) return;
    const int g = lane >> 3;
    const int l = lane & 7;
    float* outp = out + (size_t)wid * OUT_DIM + l * 16 + g * 2;

    int base = offs2[wid];
    int len = offs2[wid + 1] - base;
    if (len == 0) {
        *(float2*)outp = make_float2(0.f, 0.f);
        return;
    }
    const float s2v = s2[wid];

    float sum = 0.f;
    f32x2 acc2[8];
#pragma unroll
    for (int k = 0; k < 8; k++) acc2[k] = (f32x2){0.f, 0.f};

    for (int c0 = 0; c0 < len; c0 += 64) {
        int i = c0 + lane;
        float ex = 0.f;
        int sj = 0;
        if (i < len) {
            sj = srcs[base + i];
            float lg = s1[sj] + s2v;
            lg = (lg >= 0.f) ? lg : ALPHA * lg;
            ex = __expf(lg);
        }
        sum += ex;
        int cnt = min(64, len - c0);
        int j0 = 0;
        for (; j0 + 16 <= cnt; j0 += 16) {
            int ja = j0 + g, jb = j0 + 8 + g;
            float wa = __shfl(ex, ja), wb = __shfl(ex, jb);
            int sa = __shfl(sj, ja), sb = __shfl(sj, jb);
            const uint4* rpa = (const uint4*)(zb + (size_t)sa * OUT_DIM);
            const uint4* rpb = (const uint4*)(zb + (size_t)sb * OUT_DIM);
            const uint4 a0 = rpa[l * 2];
            const uint4 a1 = rpa[l * 2 + 1];
            const uint4 b0 = rpb[l * 2];
            const uint4 b1 = rpb[l * 2 + 1];
#pragma unroll
            for (int k = 0; k < 4; k++) {
                unsigned int u = (&a0.x)[k];
                f32x2 f;
                f.x = __uint_as_float(u << 16);
                f.y = __uint_as_float(u & 0xFFFF0000u);
                acc2[k] += wa * f;
                u = (&b0.x)[k];
                f.x = __uint_as_float(u << 16);
                f.y = __uint_as_float(u & 0xFFFF0000u);
                acc2[k] += wb * f;
            }
#pragma unroll
            for (int k = 0; k < 4; k++) {
                unsigned int u = (&a1.x)[k];
                f32x2 f;
                f.x = __uint_as_float(u << 16);
                f.y = __uint_as_float(u & 0xFFFF0000u);
                acc2[4 + k] += wa * f;
                u = (&b1.x)[k];
                f.x = __uint_as_float(u << 16);
                f.y = __uint_as_float(u & 0xFFFF0000u);
                acc2[4 + k] += wb * f;
            }
        }
        for (; j0 < cnt; j0 += 8) {
            int j = j0 + g;
            float wj = __shfl(ex, j);
            int s = __shfl(sj, j);
            if (j < cnt) {
                const uint4* rp = (const uint4*)(zb + (size_t)s * OUT_DIM);
                const uint4 v0 = rp[l * 2];
                const uint4 v1 = rp[l * 2 + 1];
#pragma unroll
                for (int k = 0; k < 4; k++) {
                    unsigned int u = (&v0.x)[k];
                    f32x2 f;
                    f.x = __uint_as_float(u << 16);
                    f.y = __uint_as_float(u & 0xFFFF0000u);
                    acc2[k] += wj * f;
                }
#pragma unroll
                for (int k = 0; k < 4; k++) {
                    unsigned int u = (&v1.x)[k];
                    f32x2 f;
                    f.x = __uint_as_float(u << 16);
                    f.y = __uint_as_float(u & 0xFFFF0000u);
                    acc2[4 + k] += wj * f;
                }
            }
        }
    }
#pragma unroll
    for (int k = 0; k < 8; k++) {
        acc2[k].x += __shfl_xor(acc2[k].x, 8);
        acc2[k].y += __shfl_xor(acc2[k].y, 8);
        acc2[k].x += __shfl_xor(acc2[k].x, 16);
        acc2[k].y += __shfl_xor(acc2[k].y, 16);
        acc2[k].x += __shfl_xor(acc2[k].x, 32);
        acc2[k].y += __shfl_xor(acc2[k].y, 32);
    }
#pragma unroll
    for (int m = 32; m >= 1; m >>= 1) sum += __shfl_xor(sum, m);
    float inv = (sum > 0.f) ? 1.f / sum : 1.f;

    float a0 = acc2[g].x * inv;
    float a1 = acc2[g].y * inv;
    float2 o;
    o.x = (a0 > 0.f) ? a0 : expm1f(a0);
    o.y = (a1 > 0.f) ? a1 : expm1f(a1);
    *(float2*)outp = o;
}

// ---------------- launcher ----------------
extern "C" void kernel_launch(void* const* d_in, const int* in_sizes, int n_in,
                              void* d_out, int out_size, void* d_ws, size_t ws_size,
                              hipStream_t stream) {
    const float* h      = (const float*)d_in[0];
    const int*   src    = (const int*)d_in[1];
    const int*   dst    = (const int*)d_in[2];
    const float* W_fc   = (const float*)d_in[3];
    const float* attn_w = (const float*)d_in[4];
    float* out = (float*)d_out;

    char* ws = (char*)d_ws;
    unsigned short* zb = (unsigned short*)(ws + OFF_ZB);
    float* s1       = (float*)(ws + OFF_S1);
    float* s2       = (float*)(ws + OFF_S2);
    int*   offs2    = (int*)(ws + OFF_OFFS2);
    unsigned short* WT = (unsigned short*)(ws + OFF_WT);
    int*   hist     = (int*)(ws + OFF_HIST);
    int*   bbase    = (int*)(ws + OFF_BBASE);
    int*   btot     = (int*)(ws + OFF_BTOT);
    unsigned int* tmp = (unsigned int*)(ws + OFF_TMP);
    unsigned short* srcs = (unsigned short*)(ws + OFF_SRCS);

    wt_k<<<16, 256, 0, stream>>>(W_fc, WT);
    gemm_hist<<<GEMM_NB + HIST_NB, 512, 0, stream>>>(h, WT, attn_w, zb, s1, s2, dst, hist);
    colscan<<<BKT, 256, 0, stream>>>(hist, bbase, btot);
    scatter_b<<<HIST_NB, 512, 0, stream>>>(src, dst, bbase, btot, tmp);
    bucket_sort<<<BKT, 512, 0, stream>>>(tmp, btot, srcs, offs2);
    aggregate<<<(N_NODES * 64) / 256, 256, 0, stream>>>(zb, offs2, srcs, s1, s2, out);
}